// Round 1
// baseline (204.862 us; speedup 1.0000x reference)
//
#include <hip/hip_runtime.h>

#define TL 2048
#define NHEAD 8
#define NLOC 4

typedef __attribute__((ext_vector_type(4))) float f32x4;
typedef __attribute__((ext_vector_type(8))) __bf16 bf16x8;
typedef __attribute__((ext_vector_type(8))) unsigned short u16x8;

static __device__ __forceinline__ unsigned short f2bf(float f) {
    unsigned u = __float_as_uint(f);
    u = (u + 0x7FFFu + ((u >> 16) & 1u)) >> 16;
    return (unsigned short)u;
}

// rel_scores[h', r] = dot(rel_pos_w[r, h'*64 : h'*64+64], mlp_w[h'])
__global__ __launch_bounds__(256) void relscore_kernel(
    const float* __restrict__ rel_pos_w, const float* __restrict__ mlp_w,
    float* __restrict__ rel_s) {
    int r = blockIdx.x;      // 0..4094
    int t = threadIdx.x;     // wave = h' (t>>6), lane = d (t&63)
    int w = t >> 6, lane = t & 63;
    float v = rel_pos_w[r * 256 + t] * mlp_w[t];
#pragma unroll
    for (int off = 32; off; off >>= 1) v += __shfl_xor(v, off);
    if (lane == 0) rel_s[w * 4095 + r] = v;
}

// v_term[(b*4+h')*L + k] = dot(value[b, 4+h', k, :], mlp_w[h'])
__global__ __launch_bounds__(256) void vterm_kernel(
    const float* __restrict__ value, const float* __restrict__ mlp_w,
    float* __restrict__ vt) {
    int t = threadIdx.x;
    int lane = t & 63;
    int w = blockIdx.x * 4 + (t >> 6);   // 0 .. B*4*L-1
    int k = w & (TL - 1);
    int hp = (w >> 11) & 3;
    int b = w >> 13;
    float v = value[((size_t)((b * NHEAD + NLOC + hp) * TL + k) << 6) + lane] *
              mlp_w[hp * 64 + lane];
#pragma unroll
    for (int off = 32; off; off >>= 1) v += __shfl_xor(v, off);
    if (lane == 0) vt[w] = v;
}

// Flash attention, 1 block = 1 (b,h) x 64 q-rows; 4 waves x 16 q each.
// Swapped MFMA: S^T = mfma(K_frag, Q_frag) -> per-lane q = lane&15.
__global__ __launch_bounds__(256, 2) void attn_kernel(
    const float* __restrict__ query, const float* __restrict__ key,
    const float* __restrict__ value, const float* __restrict__ rel_s,
    const float* __restrict__ vt, float* __restrict__ out) {

    __shared__ __align__(16) unsigned char smem[44288];
    unsigned short* Ks = (unsigned short*)smem;            // [64][72] bf16, k-major
    unsigned short* Vt = (unsigned short*)(smem + 9216);   // [64][72] bf16, d-major (transposed V)
    unsigned short* Pb = (unsigned short*)(smem + 18432);  // per-wave [16][72] bf16
    float* relb  = (float*)(smem + 27648);                 // [4095]
    float* biask = (float*)(smem + 44028);                 // [64]

    int bid = blockIdx.x;
    int bh = bid >> 5;                 // (b,h) major: L2 locality for K/V
    int qb = 31 - (bid & 31);          // heavy q-blocks dispatched first
    int h = bh & 7;
    int b = bh >> 3;
    int q0 = qb << 6;
    int t = threadIdx.x;
    int wave = t >> 6, lane = t & 63;
    int l15 = lane & 15, l4 = lane >> 4;
    bool islocal = (h >= NLOC);

    size_t base = (size_t)bh * TL * 64;
    const float* Qp = query + base;
    const float* Kp = key + base;
    const float* Vp = value + base;

    if (islocal) {
        for (int i = t; i < 4095; i += 256) relb[i] = rel_s[(h - NLOC) * 4095 + i];
    }

    int qt = q0 + wave * 16;
    int q = qt + l15;

    // Q fragments (b-operand layout: lane = q + 16*kb, 8 contiguous d)
    bf16x8 qf0, qf1;
    {
        const float* qsrc = Qp + (size_t)q * 64 + l4 * 8;
        f32x4 a = *(const f32x4*)qsrc;
        f32x4 bb = *(const f32x4*)(qsrc + 4);
        f32x4 c = *(const f32x4*)(qsrc + 32);
        f32x4 d = *(const f32x4*)(qsrc + 36);
        u16x8 u0, u1;
#pragma unroll
        for (int j = 0; j < 4; ++j) {
            u0[j] = f2bf(a[j]); u0[4 + j] = f2bf(bb[j]);
            u1[j] = f2bf(c[j]); u1[4 + j] = f2bf(d[j]);
        }
        qf0 = __builtin_bit_cast(bf16x8, u0);
        qf1 = __builtin_bit_cast(bf16x8, u1);
    }

    float m = -1e30f, lsum = 0.0f;
    f32x4 acc0 = {0.f, 0.f, 0.f, 0.f};
    f32x4 acc1 = acc0, acc2 = acc0, acc3 = acc0;
    unsigned short* Pw = Pb + wave * (16 * 72);

    int r16 = t >> 4, c4 = (t & 15) << 2;
    int vtbase = islocal ? ((b * NLOC + (h - NLOC)) * TL) : 0;

    for (int kt = 0; kt <= qb; ++kt) {
        int k0 = kt << 6;
        __syncthreads();
        // ---- stage K (row-major bf16) and V (transposed, d-major bf16) ----
#pragma unroll
        for (int rr = 0; rr < 4; ++rr) {
            int row = rr * 16 + r16;
            f32x4 kv = *(const f32x4*)(Kp + (size_t)(k0 + row) * 64 + c4);
            unsigned long long pk =
                (unsigned long long)f2bf(kv[0]) |
                ((unsigned long long)f2bf(kv[1]) << 16) |
                ((unsigned long long)f2bf(kv[2]) << 32) |
                ((unsigned long long)f2bf(kv[3]) << 48);
            *(unsigned long long*)&Ks[row * 72 + c4] = pk;
            f32x4 vv = *(const f32x4*)(Vp + (size_t)(k0 + row) * 64 + c4);
            Vt[(c4 + 0) * 72 + row] = f2bf(vv[0]);
            Vt[(c4 + 1) * 72 + row] = f2bf(vv[1]);
            Vt[(c4 + 2) * 72 + row] = f2bf(vv[2]);
            Vt[(c4 + 3) * 72 + row] = f2bf(vv[3]);
        }
        if (islocal && t < 64) biask[t] = vt[vtbase + k0 + t];
        __syncthreads();

        // ---- S^T tiles: row = k (16/sub-tile), col = q ----
        f32x4 sfr[4];
#pragma unroll
        for (int s16 = 0; s16 < 4; ++s16) {
            const bf16x8 kf0 = *(const bf16x8*)&Ks[(s16 * 16 + l15) * 72 + l4 * 8];
            const bf16x8 kf1 = *(const bf16x8*)&Ks[(s16 * 16 + l15) * 72 + 32 + l4 * 8];
            f32x4 z = {0.f, 0.f, 0.f, 0.f};
            z = __builtin_amdgcn_mfma_f32_16x16x32_bf16(kf0, qf0, z, 0, 0, 0);
            z = __builtin_amdgcn_mfma_f32_16x16x32_bf16(kf1, qf1, z, 0, 0, 0);
            sfr[s16] = z;
        }

        // ---- online softmax over this 64-k tile (per-lane row state) ----
        float sv[16];
        float tmax = -1e30f;
#pragma unroll
        for (int s16 = 0; s16 < 4; ++s16) {
#pragma unroll
            for (int rg = 0; rg < 4; ++rg) {
                int k = k0 + s16 * 16 + l4 * 4 + rg;
                float s = sfr[s16][rg] * 0.125f;
                if (islocal) s += relb[k - q + 2047] + biask[k - k0];
                s = (k <= q) ? s : -1e30f;
                sv[s16 * 4 + rg] = s;
                tmax = fmaxf(tmax, s);
            }
        }
        tmax = fmaxf(tmax, __shfl_xor(tmax, 16));
        tmax = fmaxf(tmax, __shfl_xor(tmax, 32));
        float newm = fmaxf(m, tmax);
        float corr = __expf(m - newm);
        float psum = 0.f;
        unsigned short pu[16];
#pragma unroll
        for (int i = 0; i < 16; ++i) {
            float p = __expf(sv[i] - newm);
            psum += p;
            pu[i] = f2bf(p);
        }
        psum += __shfl_xor(psum, 16);
        psum += __shfl_xor(psum, 32);
        lsum = lsum * corr + psum;
        m = newm;
        acc0 *= corr; acc1 *= corr; acc2 *= corr; acc3 *= corr;

        // ---- write P^T as [q][k] bf16 (wave-private, no barrier needed) ----
#pragma unroll
        for (int s16 = 0; s16 < 4; ++s16) {
            unsigned long long pk =
                (unsigned long long)pu[s16 * 4 + 0] |
                ((unsigned long long)pu[s16 * 4 + 1] << 16) |
                ((unsigned long long)pu[s16 * 4 + 2] << 32) |
                ((unsigned long long)pu[s16 * 4 + 3] << 48);
            *(unsigned long long*)&Pw[l15 * 72 + s16 * 16 + l4 * 4] = pk;
        }

        // ---- PV: O^T[d][q] += V^T[d][k] * P[q][k] ----
#pragma unroll
        for (int half = 0; half < 2; ++half) {
            const bf16x8 pf = *(const bf16x8*)&Pw[l15 * 72 + half * 32 + l4 * 8];
            const bf16x8 vf0 = *(const bf16x8*)&Vt[(0 + l15) * 72 + half * 32 + l4 * 8];
            const bf16x8 vf1 = *(const bf16x8*)&Vt[(16 + l15) * 72 + half * 32 + l4 * 8];
            const bf16x8 vf2 = *(const bf16x8*)&Vt[(32 + l15) * 72 + half * 32 + l4 * 8];
            const bf16x8 vf3 = *(const bf16x8*)&Vt[(48 + l15) * 72 + half * 32 + l4 * 8];
            acc0 = __builtin_amdgcn_mfma_f32_16x16x32_bf16(vf0, pf, acc0, 0, 0, 0);
            acc1 = __builtin_amdgcn_mfma_f32_16x16x32_bf16(vf1, pf, acc1, 0, 0, 0);
            acc2 = __builtin_amdgcn_mfma_f32_16x16x32_bf16(vf2, pf, acc2, 0, 0, 0);
            acc3 = __builtin_amdgcn_mfma_f32_16x16x32_bf16(vf3, pf, acc3, 0, 0, 0);
        }
    }

    // ---- epilogue: O^T -> LDS -> coalesced f32 stores ----
    __syncthreads();   // everyone done with Ks/Vt; reuse as per-wave f32 [16][68]
    float invl = 1.0f / lsum;
    float* ob = (float*)(smem + wave * 4352);
    *(f32x4*)&ob[l15 * 68 + 0 + l4 * 4] = acc0 * invl;
    *(f32x4*)&ob[l15 * 68 + 16 + l4 * 4] = acc1 * invl;
    *(f32x4*)&ob[l15 * 68 + 32 + l4 * 4] = acc2 * invl;
    *(f32x4*)&ob[l15 * 68 + 48 + l4 * 4] = acc3 * invl;
    // same-wave LDS round-trip (compiler inserts lgkmcnt wait)
    size_t obase = base + (size_t)qt * 64;
#pragma unroll
    for (int it = 0; it < 4; ++it) {
        int row = lane >> 2;
        int col = (lane & 3) * 16 + it * 4;
        f32x4 o = *(const f32x4*)&ob[row * 68 + col];
        *(f32x4*)(out + obase + (size_t)row * 64 + col) = o;
    }
}

extern "C" void kernel_launch(void* const* d_in, const int* in_sizes, int n_in,
                              void* d_out, int out_size, void* d_ws, size_t ws_size,
                              hipStream_t stream) {
    const float* query = (const float*)d_in[0];
    const float* key = (const float*)d_in[1];
    const float* value = (const float*)d_in[2];
    const float* rel_pos_w = (const float*)d_in[5];
    const float* mlp_w = (const float*)d_in[8];
    float* out = (float*)d_out;

    float* rel_s = (float*)d_ws;        // 4*4095 floats (16384 slot)
    float* vt = rel_s + 16384;          // 4*4*2048 floats

    relscore_kernel<<<4095, 256, 0, stream>>>(rel_pos_w, mlp_w, rel_s);
    vterm_kernel<<<8192, 256, 0, stream>>>(value, mlp_w, vt);
    attn_kernel<<<1024, 256, 0, stream>>>(query, key, value, rel_s, vt, out);
}